// Round 1
// baseline (41.696 us; speedup 1.0000x reference)
//
#include <hip/hip_runtime.h>
#include <math.h>

#define BB 4096
#define CC 1000
#define DD 1024
#define SCALEF 100.0f

__device__ inline float wave_reduce(float v) {
#pragma unroll
    for (int off = 32; off > 0; off >>= 1) v += __shfl_down(v, off);
    return v;
}

// Per feature row b: compute ||f_b||, ||q_{t_b}||, f_b . q_{t_b}
// writes rnorm[b] = 1/||f_b||, p[b] = cos(f_b, q_{t_b})
__global__ __launch_bounds__(256) void k_rows(const float* __restrict__ feature,
                                              const float* __restrict__ query,
                                              const int* __restrict__ target,
                                              float* __restrict__ rnorm,
                                              float* __restrict__ p) {
    int b = blockIdx.x;
    int t = threadIdx.x;
    int tb = target[b];
    const float4* frow = (const float4*)(feature + (size_t)b * DD);
    const float4* qrow = (const float4*)(query + (size_t)tb * DD);
    float4 x = frow[t];
    float4 q = qrow[t];
    float nf = x.x * x.x + x.y * x.y + x.z * x.z + x.w * x.w;
    float nq = q.x * q.x + q.y * q.y + q.z * q.z + q.w * q.w;
    float dt = x.x * q.x + x.y * q.y + x.z * q.z + x.w * q.w;

    nf = wave_reduce(nf);
    nq = wave_reduce(nq);
    dt = wave_reduce(dt);

    __shared__ float red[4][3];
    int wave = threadIdx.x >> 6, lane = threadIdx.x & 63;
    if (lane == 0) { red[wave][0] = nf; red[wave][1] = nq; red[wave][2] = dt; }
    __syncthreads();
    if (t == 0) {
        float a = 0.f, bq = 0.f, c = 0.f;
#pragma unroll
        for (int w = 0; w < 4; ++w) { a += red[w][0]; bq += red[w][1]; c += red[w][2]; }
        float rn = rsqrtf(a);
        rnorm[b] = rn;
        p[b] = c * rn * rsqrtf(bq);
    }
}

// S[d] = sum_b feature[b][d] * rnorm[b]   (S pre-zeroed via memset)
__global__ __launch_bounds__(256) void k_colsum(const float* __restrict__ feature,
                                                const float* __restrict__ rnorm,
                                                float* __restrict__ S) {
    int dblk = blockIdx.x & 3;
    int chunk = blockIdx.x >> 2;
    int d = dblk * 256 + threadIdx.x;
    int b0 = chunk * 64;
    float acc = 0.f;
#pragma unroll 4
    for (int b = b0; b < b0 + 64; ++b)
        acc += feature[(size_t)b * DD + d] * rnorm[b];
    atomicAdd(&S[d], acc);
}

// nnval[c] = (10/B) * (S . q_c) / ||q_c||
__global__ __launch_bounds__(256) void k_nnval(const float* __restrict__ query,
                                               const float* __restrict__ S,
                                               float* __restrict__ nnval) {
    int c = blockIdx.x;
    int t = threadIdx.x;
    float4 q = ((const float4*)(query + (size_t)c * DD))[t];
    float4 s = ((const float4*)S)[t];
    float nq = q.x * q.x + q.y * q.y + q.z * q.z + q.w * q.w;
    float dt = q.x * s.x + q.y * s.y + q.z * s.z + q.w * s.w;
    nq = wave_reduce(nq);
    dt = wave_reduce(dt);
    __shared__ float red[4][2];
    int wave = threadIdx.x >> 6, lane = threadIdx.x & 63;
    if (lane == 0) { red[wave][0] = nq; red[wave][1] = dt; }
    __syncthreads();
    if (t == 0) {
        float a = 0.f, b = 0.f;
#pragma unroll
        for (int w = 0; w < 4; ++w) { a += red[w][0]; b += red[w][1]; }
        nnval[c] = (10.0f / (float)BB) * b * rsqrtf(a);
    }
}

// Single block: stable counting sort of target (perm), then
// loss = mean_i softplus(SCALE*(nnval[target[i]] - p[perm[i]]))
__global__ __launch_bounds__(1024) void k_final(const int* __restrict__ target,
                                                const float* __restrict__ p,
                                                const float* __restrict__ nnval,
                                                float* __restrict__ out) {
    __shared__ int tgt[BB];      // 16KB
    __shared__ int order[BB];    // 16KB
    __shared__ int cnts[1024];   // histogram, then running offsets
    __shared__ int sbuf[1024];   // scan buffer
    __shared__ int starts[1024];

    int tid = threadIdx.x;

    for (int i = tid; i < BB; i += 1024) tgt[i] = target[i];
    cnts[tid] = 0;
    __syncthreads();

    // histogram
    for (int i = tid; i < BB; i += 1024) atomicAdd(&cnts[tgt[i]], 1);
    __syncthreads();

    // exclusive scan over 1024 (classes padded with zeros)
    int v = cnts[tid];
    sbuf[tid] = v;
    __syncthreads();
    for (int off = 1; off < 1024; off <<= 1) {
        int t = 0;
        if (tid >= off) t = sbuf[tid - off];
        __syncthreads();
        sbuf[tid] += t;
        __syncthreads();
    }
    starts[tid] = sbuf[tid] - v;  // exclusive prefix
    cnts[tid] = 0;                // reuse as running offsets
    __syncthreads();

    // scatter (arbitrary order within class)
    for (int i = tid; i < BB; i += 1024) {
        int c = tgt[i];
        int j = atomicAdd(&cnts[c], 1);
        order[starts[c] + j] = i;
    }
    __syncthreads();

    // per-class insertion sort -> stable order (ascending index within class)
    if (tid < CC) {
        int s = starts[tid], n = cnts[tid];
        for (int a = 1; a < n; ++a) {
            int key = order[s + a];
            int bb = a - 1;
            while (bb >= 0 && order[s + bb] > key) {
                order[s + bb + 1] = order[s + bb];
                --bb;
            }
            order[s + bb + 1] = key;
        }
    }
    __syncthreads();

    // final reduction
    float acc = 0.f;
    for (int i = tid; i < BB; i += 1024) {
        int b = order[i];
        float d = SCALEF * (nnval[tgt[i]] - p[b]);
        float term = (d > 0.f) ? (d + log1pf(expf(-d))) : log1pf(expf(d));
        acc += term;
    }
    acc = wave_reduce(acc);
    __shared__ float fred[16];
    int wave = tid >> 6, lane = tid & 63;
    if (lane == 0) fred[wave] = acc;
    __syncthreads();
    if (tid == 0) {
        float s = 0.f;
#pragma unroll
        for (int w = 0; w < 16; ++w) s += fred[w];
        out[0] = s / (float)BB;
    }
}

extern "C" void kernel_launch(void* const* d_in, const int* in_sizes, int n_in,
                              void* d_out, int out_size, void* d_ws, size_t ws_size,
                              hipStream_t stream) {
    const float* feature = (const float*)d_in[0];
    const float* query   = (const float*)d_in[1];
    const int*   target  = (const int*)d_in[2];
    float* out = (float*)d_out;
    float* ws  = (float*)d_ws;

    float* rnorm = ws;            // 4096
    float* p     = ws + 4096;     // 4096
    float* S     = ws + 8192;     // 1024
    float* nnval = ws + 9216;     // 1000

    hipMemsetAsync(S, 0, DD * sizeof(float), stream);
    k_rows<<<BB, 256, 0, stream>>>(feature, query, target, rnorm, p);
    k_colsum<<<256, 256, 0, stream>>>(feature, rnorm, S);
    k_nnval<<<CC, 256, 0, stream>>>(query, S, nnval);
    k_final<<<1, 1024, 0, stream>>>(target, p, nnval, out);
}

// Round 2
// 36.247 us; speedup vs baseline: 1.1503x; 1.1503x over previous
//
#include <hip/hip_runtime.h>
#include <math.h>

#define BB 4096
#define CC 1000
#define DD 1024
#define NPART 1024          // row blocks (4 rows each); block NPART does the sort
#define ROWS_PER_BLK 4
#define SCALEF 100.0f

__device__ inline float wave_reduce(float v) {
#pragma unroll
    for (int off = 32; off > 0; off >>= 1) v += __shfl_down(v, off);
    return v;
}

// Fused: blocks 0..NPART-1 -> per-row 1/||f||, p[b]=cos(f_b,q_{t_b}), and
// partialS[blk][d] = sum over its 4 rows of f[b][d]/||f_b||.
// Block NPART -> stable counting sort of target into order[], and zeroes S.
__global__ __launch_bounds__(256) void k_fused(const float* __restrict__ feature,
                                               const float* __restrict__ query,
                                               const int* __restrict__ target,
                                               float* __restrict__ p,
                                               float* __restrict__ partialS,
                                               float* __restrict__ S,
                                               int* __restrict__ order) {
    __shared__ float red[4][3];
    __shared__ float s_rn;
    __shared__ unsigned short s_tgt[BB];   // 8KB
    __shared__ unsigned short s_ord[BB];   // 8KB
    __shared__ int s_cnt[1024];            // 4KB
    __shared__ int s_start[1024];          // 4KB
    __shared__ int s_wsum[4];

    int tid = threadIdx.x;

    if (blockIdx.x == NPART) {
        // ---- sort block ----
        for (int i = tid; i < 1024; i += 256) s_cnt[i] = 0;
        for (int i = tid; i < BB; i += 256) s_tgt[i] = (unsigned short)target[i];
        for (int i = tid; i < DD; i += 256) S[i] = 0.f;   // zero S for reduceS atomics
        __syncthreads();
        for (int i = tid; i < BB; i += 256) atomicAdd(&s_cnt[s_tgt[i]], 1);
        __syncthreads();
        // exclusive scan of 1024 bins: 4 bins/thread + wave shfl-scan
        int b4 = tid * 4;
        int c0 = s_cnt[b4], c1 = s_cnt[b4 + 1], c2 = s_cnt[b4 + 2], c3 = s_cnt[b4 + 3];
        int tot = c0 + c1 + c2 + c3;
        int lane = tid & 63, wv = tid >> 6;
        int inc = tot;
#pragma unroll
        for (int off = 1; off < 64; off <<= 1) {
            int t = __shfl_up(inc, off);
            if (lane >= off) inc += t;
        }
        if (lane == 63) s_wsum[wv] = inc;
        __syncthreads();
        int wpre = 0;
        for (int w = 0; w < wv; ++w) wpre += s_wsum[w];
        int excl = wpre + inc - tot;
        s_start[b4] = excl;
        s_start[b4 + 1] = excl + c0;
        s_start[b4 + 2] = excl + c0 + c1;
        s_start[b4 + 3] = excl + c0 + c1 + c2;
        s_cnt[b4] = 0; s_cnt[b4 + 1] = 0; s_cnt[b4 + 2] = 0; s_cnt[b4 + 3] = 0;
        __syncthreads();
        // scatter (unordered within class)
        for (int i = tid; i < BB; i += 256) {
            int c = s_tgt[i];
            int j = atomicAdd(&s_cnt[c], 1);
            s_ord[s_start[c] + j] = (unsigned short)i;
        }
        __syncthreads();
        // stabilize: tiny insertion sort per class (~4 elems avg)
        for (int c = tid; c < 1024; c += 256) {
            int s = s_start[c], n = s_cnt[c];
            for (int a = 1; a < n; ++a) {
                unsigned short key = s_ord[s + a];
                int j = a - 1;
                while (j >= 0 && s_ord[s + j] > key) { s_ord[s + j + 1] = s_ord[s + j]; --j; }
                s_ord[s + j + 1] = key;
            }
        }
        __syncthreads();
        for (int i = tid; i < BB; i += 256) order[i] = (int)s_ord[i];
        return;
    }

    // ---- row blocks ----
    int b0 = blockIdx.x * ROWS_PER_BLK;
    float4 acc = make_float4(0.f, 0.f, 0.f, 0.f);
    int wv = tid >> 6, lane = tid & 63;
    for (int r = 0; r < ROWS_PER_BLK; ++r) {
        int b = b0 + r;
        int tb = target[b];
        float4 x = ((const float4*)(feature + (size_t)b * DD))[tid];
        float4 q = ((const float4*)(query + (size_t)tb * DD))[tid];
        float nf = x.x * x.x + x.y * x.y + x.z * x.z + x.w * x.w;
        float nq = q.x * q.x + q.y * q.y + q.z * q.z + q.w * q.w;
        float dt = x.x * q.x + x.y * q.y + x.z * q.z + x.w * q.w;
        nf = wave_reduce(nf);
        nq = wave_reduce(nq);
        dt = wave_reduce(dt);
        if (lane == 0) { red[wv][0] = nf; red[wv][1] = nq; red[wv][2] = dt; }
        __syncthreads();
        if (tid == 0) {
            float a = red[0][0] + red[1][0] + red[2][0] + red[3][0];
            float bq = red[0][1] + red[1][1] + red[2][1] + red[3][1];
            float c = red[0][2] + red[1][2] + red[2][2] + red[3][2];
            float rn = rsqrtf(a);
            s_rn = rn;
            p[b] = c * rn * rsqrtf(bq);
        }
        __syncthreads();
        float rn = s_rn;
        acc.x += x.x * rn; acc.y += x.y * rn; acc.z += x.z * rn; acc.w += x.w * rn;
    }
    ((float4*)(partialS + (size_t)blockIdx.x * DD))[tid] = acc;
}

// S[d] = sum_b partialS[b][d] ; 128 blocks x 256 -> 32 groups of 32 partials per d
__global__ __launch_bounds__(256) void k_reduceS(const float* __restrict__ partialS,
                                                 float* __restrict__ S) {
    int gtid = blockIdx.x * 256 + threadIdx.x;
    int d = gtid & 1023;
    int grp = gtid >> 10;   // 0..31
    float acc = 0.f;
#pragma unroll 8
    for (int b = grp * 32; b < grp * 32 + 32; ++b)
        acc += partialS[(size_t)b * DD + d];
    atomicAdd(&S[d], acc);
}

// nnval[c] = (10/B) * (S . q_c) / ||q_c||
__global__ __launch_bounds__(256) void k_nnval(const float* __restrict__ query,
                                               const float* __restrict__ S,
                                               float* __restrict__ nnval) {
    int c = blockIdx.x;
    int t = threadIdx.x;
    float4 q = ((const float4*)(query + (size_t)c * DD))[t];
    float4 s = ((const float4*)S)[t];
    float nq = q.x * q.x + q.y * q.y + q.z * q.z + q.w * q.w;
    float dt = q.x * s.x + q.y * s.y + q.z * s.z + q.w * s.w;
    nq = wave_reduce(nq);
    dt = wave_reduce(dt);
    __shared__ float red[4][2];
    int wave = t >> 6, lane = t & 63;
    if (lane == 0) { red[wave][0] = nq; red[wave][1] = dt; }
    __syncthreads();
    if (t == 0) {
        float a = 0.f, b = 0.f;
#pragma unroll
        for (int w = 0; w < 4; ++w) { a += red[w][0]; b += red[w][1]; }
        nnval[c] = (10.0f / (float)BB) * b * rsqrtf(a);
    }
}

// loss = mean_i softplus(SCALE*(nnval[target[i]] - p[order[i]]))
__global__ __launch_bounds__(1024) void k_final(const int* __restrict__ target,
                                                const int* __restrict__ order,
                                                const float* __restrict__ p,
                                                const float* __restrict__ nnval,
                                                float* __restrict__ out) {
    int tid = threadIdx.x;
    float acc = 0.f;
    for (int i = tid; i < BB; i += 1024) {
        int b = order[i];
        float d = SCALEF * (nnval[target[i]] - p[b]);
        acc += (d > 0.f) ? (d + log1pf(expf(-d))) : log1pf(expf(d));
    }
    acc = wave_reduce(acc);
    __shared__ float fred[16];
    int wave = tid >> 6, lane = tid & 63;
    if (lane == 0) fred[wave] = acc;
    __syncthreads();
    if (tid == 0) {
        float s = 0.f;
#pragma unroll
        for (int w = 0; w < 16; ++w) s += fred[w];
        out[0] = s / (float)BB;
    }
}

extern "C" void kernel_launch(void* const* d_in, const int* in_sizes, int n_in,
                              void* d_out, int out_size, void* d_ws, size_t ws_size,
                              hipStream_t stream) {
    const float* feature = (const float*)d_in[0];
    const float* query   = (const float*)d_in[1];
    const int*   target  = (const int*)d_in[2];
    float* out = (float*)d_out;
    float* ws  = (float*)d_ws;

    float* p        = ws;                      // 4096
    float* S        = ws + 4096;               // 1024
    float* nnval    = ws + 5120;               // 1000 (pad to 1024)
    int*   order    = (int*)(ws + 6144);       // 4096 ints
    float* partialS = ws + 10240;              // NPART*1024 = 4M floats

    k_fused<<<NPART + 1, 256, 0, stream>>>(feature, query, target, p, partialS, S, order);
    k_reduceS<<<128, 256, 0, stream>>>(partialS, S);
    k_nnval<<<CC, 256, 0, stream>>>(query, S, nnval);
    k_final<<<1, 1024, 0, stream>>>(target, order, p, nnval, out);
}